// Round 1
// baseline (10864.263 us; speedup 1.0000x reference)
//
#include <hip/hip_runtime.h>
#include <hip/hip_bf16.h>
#include <cstdint>
#include <cstddef>

#define BS 16
#define SEQ 3900
#define DIM 512
#define NHEAD 8
#define DH 64
#define CHUNK 200
#define NB 20
#define NR 100
#define NP 4000
#define MAXPOS 512

// bf16 helpers (bit-level, RNE)
static __device__ __forceinline__ float bf2f(unsigned short u) {
  union { unsigned int i; float f; } v; v.i = ((unsigned int)u) << 16; return v.f;
}
static __device__ __forceinline__ unsigned short f2bf(float f) {
  unsigned int x = __float_as_uint(f);
  unsigned int lsb = (x >> 16) & 1u;
  x += 0x7fffu + lsb;
  return (unsigned short)(x >> 16);
}

// ---------------------------------------------------------------------------
// Kernel 1: fused QKV projection.  y = x @ [wq | wkv], written as bf16 into
// Q/K/V workspace with padded row layout [BS][NP][DIM].
// Tiles: 64x64 per block (256 threads), 4x4 per thread, K-tile 16.
// ---------------------------------------------------------------------------
__global__ __launch_bounds__(256) void qkv_proj(
    const float* __restrict__ x, const float* __restrict__ wq,
    const float* __restrict__ wkv,
    unsigned short* __restrict__ Qb, unsigned short* __restrict__ Kb,
    unsigned short* __restrict__ Vb)
{
  __shared__ __align__(16) float As[16][64];
  __shared__ __align__(16) float Bs[16][64];
  const int tid = threadIdx.x;
  const int tx = tid & 15, ty = tid >> 4;
  const int n0 = blockIdx.x * 64;      // 0..1535
  const int m0 = blockIdx.y * 64;      // 0..62336

  // B source select (block never straddles regions: 64 | 512)
  const float* Wsrc; int ldw, c0;
  unsigned short* dst; int dc0;
  if (n0 < 512)       { Wsrc = wq;  ldw = 512;  c0 = n0;       dst = Qb; dc0 = n0; }
  else if (n0 < 1024) { Wsrc = wkv; ldw = 1024; c0 = n0 - 512; dst = Kb; dc0 = n0 - 512; }
  else                { Wsrc = wkv; ldw = 1024; c0 = n0 - 512; dst = Vb; dc0 = n0 - 1024; }

  const int lm = tid >> 2, lq = tid & 3;             // A-load: row, k-quad
  const float* aptr = x + (size_t)(m0 + lm) * DIM + lq * 4;
  const int bn = tid & 63;                           // B-load: col
  const int bk0 = (tid >> 6) * 4;                    // B-load: k base
  const float* bptr = Wsrc + c0 + bn;

  float acc[4][4] = {};
  for (int k0 = 0; k0 < DIM; k0 += 16) {
    float4 a4 = *reinterpret_cast<const float4*>(aptr + k0);
    float b0 = bptr[(size_t)(k0 + bk0 + 0) * ldw];
    float b1 = bptr[(size_t)(k0 + bk0 + 1) * ldw];
    float b2 = bptr[(size_t)(k0 + bk0 + 2) * ldw];
    float b3 = bptr[(size_t)(k0 + bk0 + 3) * ldw];
    As[lq*4+0][lm] = a4.x;
    As[lq*4+1][lm] = a4.y;
    As[lq*4+2][lm] = a4.z;
    As[lq*4+3][lm] = a4.w;
    Bs[bk0+0][bn] = b0;
    Bs[bk0+1][bn] = b1;
    Bs[bk0+2][bn] = b2;
    Bs[bk0+3][bn] = b3;
    __syncthreads();
#pragma unroll
    for (int kk = 0; kk < 16; ++kk) {
      float4 av = *reinterpret_cast<const float4*>(&As[kk][ty*4]);
      float4 bv = *reinterpret_cast<const float4*>(&Bs[kk][tx*4]);
      float a[4] = {av.x, av.y, av.z, av.w};
      float b[4] = {bv.x, bv.y, bv.z, bv.w};
#pragma unroll
      for (int i = 0; i < 4; ++i)
#pragma unroll
        for (int j = 0; j < 4; ++j)
          acc[i][j] = fmaf(a[i], b[j], acc[i][j]);
    }
    __syncthreads();
  }
  // epilogue: map dense row -> padded row, store bf16 (ushort4)
#pragma unroll
  for (int i = 0; i < 4; ++i) {
    int r = m0 + ty*4 + i;            // < 62400 always (975*64)
    int bb = r / SEQ;
    int t  = r - bb * SEQ;
    size_t orow = (size_t)bb * NP + t;
    ushort4 pk;
    pk.x = f2bf(acc[i][0]); pk.y = f2bf(acc[i][1]);
    pk.z = f2bf(acc[i][2]); pk.w = f2bf(acc[i][3]);
    *reinterpret_cast<ushort4*>(dst + orow * DIM + dc0 + tx*4) = pk;
  }
}

// ---------------------------------------------------------------------------
// Kernel 2: per-(batch, chunk, head) attention with relative position bias.
// LDS: K^T [64][201], V [200][64], circular rel-pos buffer [200][65],
// q row, score row, reduce scratch.  ~157 KB dynamic LDS.
// ---------------------------------------------------------------------------
#define SMEM_FLOATS (64*201 + 200*64 + 200*65 + 64 + 208 + 8 + 256)
#define SMEM_BYTES  (SMEM_FLOATS * 4)

__global__ __launch_bounds__(256) void attn_chunk(
    const unsigned short* __restrict__ Qb, const unsigned short* __restrict__ Kb,
    const unsigned short* __restrict__ Vb, const float* __restrict__ table,
    unsigned short* __restrict__ Ob)
{
  extern __shared__ float lds[];
  float* kT  = lds;                    // [64][201]  kT[d*201+j] = K[j][d]
  float* vv  = kT + 64*201;            // [200][64]
  float* tb  = vv + 200*64;            // [200][65]  circular: slot = dist%200
  float* qr  = tb + 200*65;            // [64]
  float* sr  = qr + 64;                // [208]
  float* red = sr + 208;               // [8]
  float* pv  = red + 8;                // [4][64]

  const int tid = threadIdx.x;
  const int bid = blockIdx.x;
  const int h  = bid & 7;
  const int bm = bid >> 3;
  const int m  = bm % NB;
  const int b  = bm / NB;
  const size_t rowbase = (size_t)b * NP + (size_t)m * CHUNK;
  const int lim = (m == NB - 1) ? NR : CHUNK;   // row & col limit

  // stage K^T and V (bf16 -> f32)
  for (int idx = tid; idx < CHUNK * DH; idx += 256) {
    int j = idx >> 6, d = idx & 63;
    size_t src = (rowbase + j) * DIM + (size_t)h * DH + d;
    kT[d*201 + j] = bf2f(Kb[src]);
    vv[j*64 + d]  = bf2f(Vb[src]);
  }
  // stage initial rel-pos rows: dist 313..512 (window for row i=0)
  for (int idx = tid; idx < CHUNK * DH; idx += 256) {
    int w = idx >> 6, d = idx & 63;
    int dist = 313 + w;
    tb[(dist % CHUNK)*65 + d] = table[(size_t)dist * DH + d];
  }
  __syncthreads();

  for (int i = 0; i < lim; ++i) {
    // (A) load q row; prefetch next rel-pos row to regs (threads 192..255)
    if (tid < 64) qr[tid] = bf2f(Qb[(rowbase + i) * DIM + (size_t)h * DH + tid]);
    float tpre = 0.f;
    const int nd = tid - 192;
    const bool pre = (nd >= 0) && (i + 1 < lim);
    if (pre) tpre = table[(size_t)(i + 513) * DH + nd];
    __syncthreads();

    // (B) scores: s[j] = (q.k_j + q.T[i-j+512]) * scale
    if (tid < CHUNK) {
      const int j = tid;
      float s = -INFINITY;
      if (j < lim) {
        const float* kp = kT + j;
        const float* tp = tb + ((unsigned)(i - j + MAXPOS) % CHUNK) * 65;
        float s0=0,s1=0,s2=0,s3=0,p0=0,p1=0,p2=0,p3=0;
#pragma unroll
        for (int d = 0; d < 64; d += 4) {
          float q0 = qr[d], q1 = qr[d+1], q2 = qr[d+2], q3 = qr[d+3];
          s0 = fmaf(q0, kp[(d+0)*201], s0);
          s1 = fmaf(q1, kp[(d+1)*201], s1);
          s2 = fmaf(q2, kp[(d+2)*201], s2);
          s3 = fmaf(q3, kp[(d+3)*201], s3);
          p0 = fmaf(q0, tp[d+0], p0);
          p1 = fmaf(q1, tp[d+1], p1);
          p2 = fmaf(q2, tp[d+2], p2);
          p3 = fmaf(q3, tp[d+3], p3);
        }
        s = (((s0+s1)+(s2+s3)) + ((p0+p1)+(p2+p3))) * 0.125f;
      }
      sr[j] = s;
    }
    __syncthreads();

    // (C) commit prefetched rel-pos row; wave max-reduce
    if (pre) tb[((unsigned)(i + 513) % CHUNK)*65 + nd] = tpre;
    float mv = (tid < lim) ? sr[tid] : -INFINITY;
#pragma unroll
    for (int off = 32; off; off >>= 1) mv = fmaxf(mv, __shfl_xor(mv, off));
    if ((tid & 63) == 0) red[tid >> 6] = mv;
    __syncthreads();

    // (D) exp + sum-reduce
    const float mrow = fmaxf(fmaxf(red[0], red[1]), fmaxf(red[2], red[3]));
    float p = 0.f;
    if (tid < lim) p = __expf(sr[tid] - mrow);
    float sv = p;
#pragma unroll
    for (int off = 32; off; off >>= 1) sv += __shfl_xor(sv, off);
    if ((tid & 63) == 0) red[4 + (tid >> 6)] = sv;
    if (tid < lim) sr[tid] = p;
    __syncthreads();

    // (E) PV: thread (d, g) partial over j = g mod 4
    const float denom = (red[4] + red[5]) + (red[6] + red[7]);
    const int d = tid & 63, g = tid >> 6;
    float a0 = 0.f, a1 = 0.f;
    for (int j = g; j < lim; j += 8) {
      a0 = fmaf(sr[j], vv[j*64 + d], a0);
      int j2 = j + 4;
      if (j2 < lim) a1 = fmaf(sr[j2], vv[j2*64 + d], a1);
    }
    pv[g*64 + d] = a0 + a1;
    __syncthreads();

    // (F) reduce 4 partials, normalize, store bf16 (aliases Q slice, safe)
    if (tid < 64) {
      float o = ((pv[tid] + pv[64+tid]) + (pv[128+tid] + pv[192+tid])) / denom;
      Ob[(rowbase + i) * DIM + (size_t)h * DH + tid] = f2bf(o);
    }
    __syncthreads();
  }
}

// ---------------------------------------------------------------------------
// Kernel 3: output projection.  out = O[:, :3900, :] @ wout_w + b  (fp32 out)
// ---------------------------------------------------------------------------
__global__ __launch_bounds__(256) void out_proj(
    const unsigned short* __restrict__ Ob, const float* __restrict__ wo,
    const float* __restrict__ bias, float* __restrict__ out)
{
  __shared__ __align__(16) float As[16][64];
  __shared__ __align__(16) float Bs[16][64];
  const int tid = threadIdx.x;
  const int tx = tid & 15, ty = tid >> 4;
  const int n0 = blockIdx.x * 64;
  const int m0 = blockIdx.y * 64;

  const int lm = tid >> 2, lq = tid & 3;
  const int ar = m0 + lm;
  const int ab = ar / SEQ;
  const int at = ar - ab * SEQ;
  const unsigned short* aptr = Ob + ((size_t)ab * NP + at) * DIM + lq * 4;
  const int bn = tid & 63;
  const int bk0 = (tid >> 6) * 4;
  const float* bptr = wo + n0 + bn;

  float acc[4][4] = {};
  for (int k0 = 0; k0 < DIM; k0 += 16) {
    ushort4 a4 = *reinterpret_cast<const ushort4*>(aptr + k0);
    float b0 = bptr[(size_t)(k0 + bk0 + 0) * DIM];
    float b1 = bptr[(size_t)(k0 + bk0 + 1) * DIM];
    float b2 = bptr[(size_t)(k0 + bk0 + 2) * DIM];
    float b3 = bptr[(size_t)(k0 + bk0 + 3) * DIM];
    As[lq*4+0][lm] = bf2f(a4.x);
    As[lq*4+1][lm] = bf2f(a4.y);
    As[lq*4+2][lm] = bf2f(a4.z);
    As[lq*4+3][lm] = bf2f(a4.w);
    Bs[bk0+0][bn] = b0;
    Bs[bk0+1][bn] = b1;
    Bs[bk0+2][bn] = b2;
    Bs[bk0+3][bn] = b3;
    __syncthreads();
#pragma unroll
    for (int kk = 0; kk < 16; ++kk) {
      float4 av = *reinterpret_cast<const float4*>(&As[kk][ty*4]);
      float4 bv = *reinterpret_cast<const float4*>(&Bs[kk][tx*4]);
      float a[4] = {av.x, av.y, av.z, av.w};
      float b[4] = {bv.x, bv.y, bv.z, bv.w};
#pragma unroll
      for (int i = 0; i < 4; ++i)
#pragma unroll
        for (int j = 0; j < 4; ++j)
          acc[i][j] = fmaf(a[i], b[j], acc[i][j]);
    }
    __syncthreads();
  }
  float4 bv4 = *reinterpret_cast<const float4*>(bias + n0 + tx*4);
#pragma unroll
  for (int i = 0; i < 4; ++i) {
    int r = m0 + ty*4 + i;   // dense row index == output row
    float4 o;
    o.x = acc[i][0] + bv4.x;
    o.y = acc[i][1] + bv4.y;
    o.z = acc[i][2] + bv4.z;
    o.w = acc[i][3] + bv4.w;
    *reinterpret_cast<float4*>(out + (size_t)r * DIM + n0 + tx*4) = o;
  }
}

// ---------------------------------------------------------------------------
extern "C" void kernel_launch(void* const* d_in, const int* in_sizes, int n_in,
                              void* d_out, int out_size, void* d_ws, size_t ws_size,
                              hipStream_t stream) {
  const float* x   = (const float*)d_in[0];
  const float* wq  = (const float*)d_in[1];
  const float* wkv = (const float*)d_in[2];
  const float* wo  = (const float*)d_in[3];
  const float* wb  = (const float*)d_in[4];
  const float* tbl = (const float*)d_in[5];
  // d_in[6] = context_size (fixed at 200 by setup_inputs; hardcoded)
  float* out = (float*)d_out;

  const size_t elems = (size_t)BS * NP * DIM;   // 32,768,000 per buffer
  unsigned short* Qb = (unsigned short*)d_ws;
  unsigned short* Kb = Qb + elems;
  unsigned short* Vb = Kb + elems;
  unsigned short* Ob = Qb;   // attention output aliases Q (disjoint-ordered access)

  hipFuncSetAttribute(reinterpret_cast<const void*>(attn_chunk),
                      hipFuncAttributeMaxDynamicSharedMemorySize, SMEM_BYTES);

  dim3 blk(256);
  qkv_proj<<<dim3(24, 975), blk, 0, stream>>>(x, wq, wkv, Qb, Kb, Vb);
  attn_chunk<<<dim3(BS * NB * NHEAD), blk, SMEM_BYTES, stream>>>(Qb, Kb, Vb, tbl, Ob);
  out_proj<<<dim3(8, 975), blk, 0, stream>>>(Ob, wo, wb, out);
}

// Round 3
// 1899.092 us; speedup vs baseline: 5.7208x; 5.7208x over previous
//
#include <hip/hip_runtime.h>
#include <hip/hip_bf16.h>
#include <cstdint>
#include <cstddef>

#define BS 16
#define SEQ 3900
#define DIM 512
#define NHEAD 8
#define DH 64
#define CHUNK 200
#define NB 20
#define NR 100
#define NP 4000
#define MAXPOS 512

typedef __attribute__((ext_vector_type(8))) short bf16x8;
typedef __attribute__((ext_vector_type(4))) float f32x4;
#define MFMA_BF16 __builtin_amdgcn_mfma_f32_16x16x32_bf16

// bf16 helpers (bit-level, RNE)
static __device__ __forceinline__ float bf2f(unsigned short u) {
  union { unsigned int i; float f; } v; v.i = ((unsigned int)u) << 16; return v.f;
}
static __device__ __forceinline__ unsigned short f2bf(float f) {
  unsigned int x = __float_as_uint(f);
  unsigned int lsb = (x >> 16) & 1u;
  x += 0x7fffu + lsb;
  return (unsigned short)(x >> 16);
}

// ---------------------------------------------------------------------------
// Kernel 0: cast the needed rel-pos table window (rows 305..720) to bf16.
// Stored in the unused pad rows of the K workspace (b=0, t in [3900,4000)).
// ---------------------------------------------------------------------------
__global__ __launch_bounds__(256) void prep_table(
    const float* __restrict__ table, unsigned short* __restrict__ Tb)
{
  int idx = (blockIdx.x * 256 + threadIdx.x) * 4;   // 26 blocks * 256 * 4 = 26624
  if (idx < 416 * 64) {
    float4 f = *reinterpret_cast<const float4*>(table + (size_t)305 * 64 + idx);
    ushort4 o;
    o.x = f2bf(f.x); o.y = f2bf(f.y); o.z = f2bf(f.z); o.w = f2bf(f.w);
    *reinterpret_cast<ushort4*>(Tb + idx) = o;
  }
}

// ---------------------------------------------------------------------------
// Kernel 1: fused QKV projection (fp32 vector GEMM, bf16 outputs).
// ---------------------------------------------------------------------------
__global__ __launch_bounds__(256) void qkv_proj(
    const float* __restrict__ x, const float* __restrict__ wq,
    const float* __restrict__ wkv,
    unsigned short* __restrict__ Qb, unsigned short* __restrict__ Kb,
    unsigned short* __restrict__ Vb)
{
  __shared__ __align__(16) float As[16][64];
  __shared__ __align__(16) float Bs[16][64];
  const int tid = threadIdx.x;
  const int tx = tid & 15, ty = tid >> 4;
  const int n0 = blockIdx.x * 64;
  const int m0 = blockIdx.y * 64;

  const float* Wsrc; int ldw, c0;
  unsigned short* dst; int dc0;
  if (n0 < 512)       { Wsrc = wq;  ldw = 512;  c0 = n0;       dst = Qb; dc0 = n0; }
  else if (n0 < 1024) { Wsrc = wkv; ldw = 1024; c0 = n0 - 512; dst = Kb; dc0 = n0 - 512; }
  else                { Wsrc = wkv; ldw = 1024; c0 = n0 - 512; dst = Vb; dc0 = n0 - 1024; }

  const int lm = tid >> 2, lq = tid & 3;
  const float* aptr = x + (size_t)(m0 + lm) * DIM + lq * 4;
  const int bn = tid & 63;
  const int bk0 = (tid >> 6) * 4;
  const float* bptr = Wsrc + c0 + bn;

  float acc[4][4] = {};
  for (int k0 = 0; k0 < DIM; k0 += 16) {
    float4 a4 = *reinterpret_cast<const float4*>(aptr + k0);
    float b0 = bptr[(size_t)(k0 + bk0 + 0) * ldw];
    float b1 = bptr[(size_t)(k0 + bk0 + 1) * ldw];
    float b2 = bptr[(size_t)(k0 + bk0 + 2) * ldw];
    float b3 = bptr[(size_t)(k0 + bk0 + 3) * ldw];
    As[lq*4+0][lm] = a4.x;
    As[lq*4+1][lm] = a4.y;
    As[lq*4+2][lm] = a4.z;
    As[lq*4+3][lm] = a4.w;
    Bs[bk0+0][bn] = b0;
    Bs[bk0+1][bn] = b1;
    Bs[bk0+2][bn] = b2;
    Bs[bk0+3][bn] = b3;
    __syncthreads();
#pragma unroll
    for (int kk = 0; kk < 16; ++kk) {
      float4 av = *reinterpret_cast<const float4*>(&As[kk][ty*4]);
      float4 bv = *reinterpret_cast<const float4*>(&Bs[kk][tx*4]);
      float a[4] = {av.x, av.y, av.z, av.w};
      float b[4] = {bv.x, bv.y, bv.z, bv.w};
#pragma unroll
      for (int i = 0; i < 4; ++i)
#pragma unroll
        for (int j = 0; j < 4; ++j)
          acc[i][j] = fmaf(a[i], b[j], acc[i][j]);
    }
    __syncthreads();
  }
#pragma unroll
  for (int i = 0; i < 4; ++i) {
    int r = m0 + ty*4 + i;
    int bb = r / SEQ;
    int t  = r - bb * SEQ;
    size_t orow = (size_t)bb * NP + t;
    ushort4 pk;
    pk.x = f2bf(acc[i][0]); pk.y = f2bf(acc[i][1]);
    pk.z = f2bf(acc[i][2]); pk.w = f2bf(acc[i][3]);
    *reinterpret_cast<ushort4*>(dst + orow * DIM + dc0 + tx*4) = pk;
  }
}

// ---------------------------------------------------------------------------
// Kernel 2: MFMA attention.  One block per (b, chunk, head); 4 waves, each
// wave owns 16-row M-tiles independently (no barriers after staging).
//   QK^T + pos-bias GEMM (Qtab) + in-register softmax + PV, all 16x16x32 bf16.
// LDS (81,920 B exactly -> 2 blocks/CU):
//   Ks[200][64] bf16, XOR-swizzled rows (byte ^= (row&7)<<4)
//   Vt[64][212] bf16 (V transposed, stride 212 for bank spread)
//   PQ: per-wave [16][228] bf16 (Qtab then P, sequentially reused)
// PV slice ks=6 (k=192..223): out-of-range fragment parts are built as ZERO
// REGISTERS (V for k>=200, P for k>=208) -- never read from LDS, so no
// uninitialized-LDS NaN can enter an MFMA (0*NaN=NaN was round-2's bug).
// ---------------------------------------------------------------------------
#define KS_U16 12800          // 200*64
#define VT_U16 13568          // 64*212
#define PQ_STR 228
#define PQ_U16 (16*PQ_STR)    // 3648 per wave
#define ATTN_LDS_B ((KS_U16 + VT_U16 + 4*PQ_U16) * 2)   // 81920

__global__ __launch_bounds__(256) void attn_mfma(
    const unsigned short* __restrict__ Qb, const unsigned short* __restrict__ Kb,
    const unsigned short* __restrict__ Vb, const unsigned short* __restrict__ Tb,
    unsigned short* __restrict__ Ob)
{
  extern __shared__ unsigned short smem[];
  unsigned short* Ks = smem;
  unsigned short* Vt = smem + KS_U16;

  const int tid = threadIdx.x;
  const int bid = blockIdx.x;
  const int h  = bid & 7;
  const int bm = bid >> 3;
  const int m  = bm % NB;
  const int b  = bm / NB;
  const size_t rowbase = (size_t)b * NP + (size_t)m * CHUNK;
  const int lim = (m == NB - 1) ? NR : CHUNK;

  // ---- stage K (swizzled) and V (transposed) ----
  for (int c = tid; c < CHUNK * 8; c += 256) {        // 200 rows x 8 chunks of 8
    int j = c >> 3, k0 = (c & 7) * 8;
    uint4 kv = *reinterpret_cast<const uint4*>(Kb + (rowbase + j) * DIM + h * DH + k0);
    int byte = (j * 128 + k0 * 2) ^ ((j & 7) << 4);
    *reinterpret_cast<uint4*>(reinterpret_cast<char*>(Ks) + byte) = kv;
    uint4 vv4 = *reinterpret_cast<const uint4*>(Vb + (rowbase + j) * DIM + h * DH + k0);
    const unsigned short* vs = reinterpret_cast<const unsigned short*>(&vv4);
#pragma unroll
    for (int e = 0; e < 8; ++e)
      Vt[(k0 + e) * 212 + j] = vs[e];
  }
  __syncthreads();

  const int wv = tid >> 6, ln = tid & 63;
  const int lr = ln & 15, lg = ln >> 4;               // col-in-tile, k/row group
  unsigned short* pq = smem + KS_U16 + VT_U16 + wv * PQ_U16;

  const int nMt = (lim + 15) >> 4;
  for (int mt = wv; mt < nMt; mt += 4) {
    const int i0 = mt << 4;

    // Q A-fragments (2 K-slices) straight from global
    const unsigned short* qp = Qb + (rowbase + i0 + lr) * DIM + h * DH + lg * 8;
    bf16x8 qa0 = *reinterpret_cast<const bf16x8*>(qp);
    bf16x8 qa1 = *reinterpret_cast<const bf16x8*>(qp + 32);

    // ---- Qtab = Q_tile @ T_window^T  (window base row = i0 in Tb coords) ----
#pragma unroll
    for (int ct = 0; ct < 14; ++ct) {
      const unsigned short* tp = Tb + (size_t)(i0 + ct * 16 + lr) * 64 + lg * 8;
      bf16x8 tb0 = *reinterpret_cast<const bf16x8*>(tp);
      bf16x8 tb1 = *reinterpret_cast<const bf16x8*>(tp + 32);
      f32x4 acc = {0.f, 0.f, 0.f, 0.f};
      acc = MFMA_BF16(qa0, tb0, acc, 0, 0, 0);
      acc = MFMA_BF16(qa1, tb1, acc, 0, 0, 0);
#pragma unroll
      for (int e = 0; e < 4; ++e)
        pq[(lg * 4 + e) * PQ_STR + ct * 16 + lr] = f2bf(acc[e]);
    }

    // ---- QK^T ----
    f32x4 s[13];
#pragma unroll
    for (int nt = 0; nt < 13; ++nt) {
      int row = nt * 16 + lr;
      int b0 = (row * 128 + lg * 16) ^ ((row & 7) << 4);
      int b1 = (row * 128 + 64 + lg * 16) ^ ((row & 7) << 4);
      bf16x8 k0 = *reinterpret_cast<const bf16x8*>(reinterpret_cast<char*>(Ks) + b0);
      bf16x8 k1 = *reinterpret_cast<const bf16x8*>(reinterpret_cast<char*>(Ks) + b1);
      f32x4 acc = {0.f, 0.f, 0.f, 0.f};
      acc = MFMA_BF16(qa0, k0, acc, 0, 0, 0);
      acc = MFMA_BF16(qa1, k1, acc, 0, 0, 0);
      s[nt] = acc;
    }

    // ---- add pos bias (gather from Qtab), scale, mask (FULL replacement) ----
#pragma unroll
    for (int nt = 0; nt < 13; ++nt) {
      int j = nt * 16 + lr;
#pragma unroll
      for (int e = 0; e < 4; ++e) {
        int r = lg * 4 + e;
        float pos = bf2f(pq[r * PQ_STR + (r - j + 207)]);
        float v = (s[nt][e] + pos) * 0.125f;
        s[nt][e] = (j < lim) ? v : -INFINITY;
      }
    }

    // ---- softmax (in-lane over 13 tiles + shfl_xor within 16-lane group) ----
    float sum[4];
#pragma unroll
    for (int e = 0; e < 4; ++e) {
      float mv = s[0][e];
#pragma unroll
      for (int nt = 1; nt < 13; ++nt) mv = fmaxf(mv, s[nt][e]);
      mv = fmaxf(mv, __shfl_xor(mv, 1));
      mv = fmaxf(mv, __shfl_xor(mv, 2));
      mv = fmaxf(mv, __shfl_xor(mv, 4));
      mv = fmaxf(mv, __shfl_xor(mv, 8));
      float sv = 0.f;
#pragma unroll
      for (int nt = 0; nt < 13; ++nt) {
        float p = __expf(s[nt][e] - mv);
        s[nt][e] = p;
        sv += p;
      }
      sv += __shfl_xor(sv, 1);
      sv += __shfl_xor(sv, 2);
      sv += __shfl_xor(sv, 4);
      sv += __shfl_xor(sv, 8);
      sum[e] = sv;
    }

    // ---- write P into pq (cols 0..207; Qtab already consumed) ----
#pragma unroll
    for (int nt = 0; nt < 13; ++nt)
#pragma unroll
      for (int e = 0; e < 4; ++e)
        pq[(lg * 4 + e) * PQ_STR + nt * 16 + lr] = f2bf(s[nt][e]);

    // ---- PV: O = P @ V  (K = 224, 7 slices; V from Vt transposed) ----
    // slice 6: V k>=200 and P k>=208 are ZERO REGISTERS, never LDS reads.
    f32x4 o[4];
#pragma unroll
    for (int nt = 0; nt < 4; ++nt) o[nt] = (f32x4){0.f, 0.f, 0.f, 0.f};
    const ushort4 zz = {0, 0, 0, 0};
#pragma unroll
    for (int ks = 0; ks < 7; ++ks) {
      union __align__(16) { struct { ushort4 lo, hi; } u; bf16x8 v; } pa;
      if (ks < 6 || lg < 2) {
        const char* pap = reinterpret_cast<const char*>(pq) + lr * (PQ_STR * 2) + ks * 64 + lg * 16;
        pa.u.lo = *reinterpret_cast<const ushort4*>(pap);
        pa.u.hi = *reinterpret_cast<const ushort4*>(pap + 8);
      } else {
        pa.u.lo = zz; pa.u.hi = zz;
      }
#pragma unroll
      for (int nt = 0; nt < 4; ++nt) {
        union __align__(16) { struct { ushort4 lo, hi; } u; bf16x8 v; } vb;
        if (ks < 6 || lg == 0) {
          const char* vbp = reinterpret_cast<const char*>(Vt) + (nt * 16 + lr) * 424 + ks * 64 + lg * 16;
          vb.u.lo = *reinterpret_cast<const ushort4*>(vbp);
          vb.u.hi = *reinterpret_cast<const ushort4*>(vbp + 8);
        } else {
          vb.u.lo = zz; vb.u.hi = zz;
        }
        o[nt] = MFMA_BF16(pa.v, vb.v, o[nt], 0, 0, 0);
      }
    }

    // ---- normalize + store (only valid rows) ----
#pragma unroll
    for (int nt = 0; nt < 4; ++nt)
#pragma unroll
      for (int e = 0; e < 4; ++e) {
        int i = i0 + lg * 4 + e;
        if (i < lim) {
          float val = o[nt][e] / sum[e];
          Ob[(rowbase + i) * DIM + h * DH + nt * 16 + lr] = f2bf(val);
        }
      }
  }
}

// ---------------------------------------------------------------------------
// Kernel 3: output projection (fp32 vector GEMM).
// ---------------------------------------------------------------------------
__global__ __launch_bounds__(256) void out_proj(
    const unsigned short* __restrict__ Ob, const float* __restrict__ wo,
    const float* __restrict__ bias, float* __restrict__ out)
{
  __shared__ __align__(16) float As[16][64];
  __shared__ __align__(16) float Bs[16][64];
  const int tid = threadIdx.x;
  const int tx = tid & 15, ty = tid >> 4;
  const int n0 = blockIdx.x * 64;
  const int m0 = blockIdx.y * 64;

  const int lm = tid >> 2, lq = tid & 3;
  const int ar = m0 + lm;
  const int ab = ar / SEQ;
  const int at = ar - ab * SEQ;
  const unsigned short* aptr = Ob + ((size_t)ab * NP + at) * DIM + lq * 4;
  const int bn = tid & 63;
  const int bk0 = (tid >> 6) * 4;
  const float* bptr = wo + n0 + bn;

  float acc[4][4] = {};
  for (int k0 = 0; k0 < DIM; k0 += 16) {
    ushort4 a4 = *reinterpret_cast<const ushort4*>(aptr + k0);
    float b0 = bptr[(size_t)(k0 + bk0 + 0) * DIM];
    float b1 = bptr[(size_t)(k0 + bk0 + 1) * DIM];
    float b2 = bptr[(size_t)(k0 + bk0 + 2) * DIM];
    float b3 = bptr[(size_t)(k0 + bk0 + 3) * DIM];
    As[lq*4+0][lm] = bf2f(a4.x);
    As[lq*4+1][lm] = bf2f(a4.y);
    As[lq*4+2][lm] = bf2f(a4.z);
    As[lq*4+3][lm] = bf2f(a4.w);
    Bs[bk0+0][bn] = b0;
    Bs[bk0+1][bn] = b1;
    Bs[bk0+2][bn] = b2;
    Bs[bk0+3][bn] = b3;
    __syncthreads();
#pragma unroll
    for (int kk = 0; kk < 16; ++kk) {
      float4 av = *reinterpret_cast<const float4*>(&As[kk][ty*4]);
      float4 bv = *reinterpret_cast<const float4*>(&Bs[kk][tx*4]);
      float a[4] = {av.x, av.y, av.z, av.w};
      float b[4] = {bv.x, bv.y, bv.z, bv.w};
#pragma unroll
      for (int i = 0; i < 4; ++i)
#pragma unroll
        for (int j = 0; j < 4; ++j)
          acc[i][j] = fmaf(a[i], b[j], acc[i][j]);
    }
    __syncthreads();
  }
  float4 bv4 = *reinterpret_cast<const float4*>(bias + n0 + tx*4);
#pragma unroll
  for (int i = 0; i < 4; ++i) {
    int r = m0 + ty*4 + i;
    float4 o;
    o.x = acc[i][0] + bv4.x;
    o.y = acc[i][1] + bv4.y;
    o.z = acc[i][2] + bv4.z;
    o.w = acc[i][3] + bv4.w;
    *reinterpret_cast<float4*>(out + (size_t)r * DIM + n0 + tx*4) = o;
  }
}

// ---------------------------------------------------------------------------
extern "C" void kernel_launch(void* const* d_in, const int* in_sizes, int n_in,
                              void* d_out, int out_size, void* d_ws, size_t ws_size,
                              hipStream_t stream) {
  const float* x   = (const float*)d_in[0];
  const float* wq  = (const float*)d_in[1];
  const float* wkv = (const float*)d_in[2];
  const float* wo  = (const float*)d_in[3];
  const float* wb  = (const float*)d_in[4];
  const float* tbl = (const float*)d_in[5];
  float* out = (float*)d_out;

  const size_t elems = (size_t)BS * NP * DIM;
  unsigned short* Qb = (unsigned short*)d_ws;
  unsigned short* Kb = Qb + elems;
  unsigned short* Vb = Kb + elems;
  unsigned short* Ob = Qb;                       // attn output aliases Q
  // bf16 table window (rows 305..720) lives in Kb's unused pad rows (b=0)
  unsigned short* Tb = Kb + (size_t)SEQ * DIM;   // 416*64 = 26624 <= 100*512 pad

  hipFuncSetAttribute(reinterpret_cast<const void*>(attn_mfma),
                      hipFuncAttributeMaxDynamicSharedMemorySize, ATTN_LDS_B);

  dim3 blk(256);
  prep_table<<<dim3(26), blk, 0, stream>>>(tbl, Tb);
  qkv_proj<<<dim3(24, 975), blk, 0, stream>>>(x, wq, wkv, Qb, Kb, Vb);
  attn_mfma<<<dim3(BS * NB * NHEAD), blk, ATTN_LDS_B, stream>>>(Qb, Kb, Vb, Tb, Ob);
  out_proj<<<dim3(8, 975), blk, 0, stream>>>(Ob, wo, wb, out);
}

// Round 4
// 484.495 us; speedup vs baseline: 22.4239x; 3.9197x over previous
//
#include <hip/hip_runtime.h>
#include <hip/hip_bf16.h>
#include <cstdint>
#include <cstddef>

#define BS 16
#define SEQ 3900
#define DIM 512
#define NHEAD 8
#define DH 64
#define CHUNK 200
#define NB 20
#define NR 100
#define NP 4000
#define MAXPOS 512
#define MD 62400              // dense rows = BS*SEQ

typedef __attribute__((ext_vector_type(8))) short bf16x8;
typedef __attribute__((ext_vector_type(8))) unsigned short u16x8;
typedef __attribute__((ext_vector_type(4))) float f32x4;
#define MFMA_BF16 __builtin_amdgcn_mfma_f32_16x16x32_bf16

// bf16 helpers
static __device__ __forceinline__ float bf2f(unsigned short u) {
  union { unsigned int i; float f; } v; v.i = ((unsigned int)u) << 16; return v.f;
}
static __device__ __forceinline__ unsigned short f2bf(float f) {   // RNE
  unsigned int x = __float_as_uint(f);
  unsigned int lsb = (x >> 16) & 1u;
  x += 0x7fffu + lsb;
  return (unsigned short)(x >> 16);
}
static __device__ __forceinline__ unsigned short f2bf_fast(float f) {  // round-half-up
  return (unsigned short)((__float_as_uint(f) + 0x8000u) >> 16);
}

// Pad-chunk addressing: row n of a [n][512] bf16 matrix stored in the pad rows
// (t=3900..3999) of a [16][4000][512] workspace buffer.  100 rows per chunk.
static __device__ __forceinline__ const unsigned short* wt_row(
    const unsigned short* base, int n) {
  unsigned ch = (unsigned)n / 100u;
  unsigned rr = (unsigned)n - ch * 100u;
  return base + (size_t)ch * (NP * DIM) + (size_t)SEQ * DIM + (size_t)rr * DIM;
}

// ---------------------------------------------------------------------------
// Kernel 0a: cast rel-pos table window (rows 305..720) to bf16 -> Kb pads(b0).
// ---------------------------------------------------------------------------
__global__ __launch_bounds__(256) void prep_table(
    const float* __restrict__ table, unsigned short* __restrict__ Tb)
{
  int idx = (blockIdx.x * 256 + threadIdx.x) * 4;
  if (idx < 416 * 64) {
    float4 f = *reinterpret_cast<const float4*>(table + (size_t)305 * 64 + idx);
    ushort4 o;
    o.x = f2bf(f.x); o.y = f2bf(f.y); o.z = f2bf(f.z); o.w = f2bf(f.w);
    *reinterpret_cast<ushort4*>(Tb + idx) = o;
  }
}

// ---------------------------------------------------------------------------
// Kernel 0b: transpose+cast W[k][n] fp32 -> Wt[n][k] bf16, scattered into the
// pad-row chunks of `base`.  64x64 tiles via LDS.
// ---------------------------------------------------------------------------
__global__ __launch_bounds__(256) void wtrans(
    const float* __restrict__ W, int ldn, int n_off,
    unsigned short* __restrict__ base)
{
  __shared__ float ts[64][65];
  const int tid = threadIdx.x;
  const int n0 = blockIdx.x * 64;
  const int k0 = blockIdx.y * 64;
  {
    int kl = tid >> 4;
    int nl = (tid & 15) * 4;
#pragma unroll
    for (int p = 0; p < 4; ++p) {
      float4 f = *reinterpret_cast<const float4*>(
          W + (size_t)(k0 + kl + p * 16) * ldn + n0 + nl);
      ts[kl + p * 16][nl + 0] = f.x;
      ts[kl + p * 16][nl + 1] = f.y;
      ts[kl + p * 16][nl + 2] = f.z;
      ts[kl + p * 16][nl + 3] = f.w;
    }
  }
  __syncthreads();
  {
    int nl = tid >> 2;
    int kof = (tid & 3) * 16;
    int n = n0 + nl + n_off;
    unsigned ch = (unsigned)n / 100u;
    unsigned rr = (unsigned)n - ch * 100u;
    unsigned short* dst = base + (size_t)ch * (NP * DIM) + (size_t)SEQ * DIM
                          + (size_t)rr * DIM + k0 + kof;
    u16x8 o0, o1;
#pragma unroll
    for (int i = 0; i < 8; ++i) o0[i] = f2bf(ts[kof + i][nl]);
#pragma unroll
    for (int i = 0; i < 8; ++i) o1[i] = f2bf(ts[kof + 8 + i][nl]);
    *reinterpret_cast<u16x8*>(dst) = o0;
    *reinterpret_cast<u16x8*>(dst + 8) = o1;
  }
}

// ---------------------------------------------------------------------------
// Kernel 1: QKV projection, bf16 MFMA.  C[62400][1536] = x(bf16) @ Wt^T.
// 128x128 tile, BK=32, 4 waves (2x2), 64x64 per wave, double-buffered LDS.
// A: x fp32 cast in-flight.  B: Wt[n][k] bf16 from Qb pads.
// ---------------------------------------------------------------------------
__global__ __launch_bounds__(256) void gemm_qkv(
    const float* __restrict__ x, const unsigned short* __restrict__ WtBase,
    unsigned short* __restrict__ Qb, unsigned short* __restrict__ Kb,
    unsigned short* __restrict__ Vb)
{
  __shared__ unsigned short As[2][128 * 40];
  __shared__ unsigned short Bs[2][128 * 40];

  int bid = blockIdx.x;                       // 5856 = 8 * 732
  bid = (bid & 7) * 732 + (bid >> 3);
  const int bm = bid / 12, bn = bid % 12;
  const int m0 = bm * 128;
  const int n0 = bn * 128;
  const int tid = threadIdx.x;

  // A-stage: thread -> (row, 16-elem half)
  const int ar = tid >> 1;
  const int ac = (tid & 1) * 16;
  int arow = m0 + ar; if (arow > MD - 1) arow = MD - 1;
  const float* ap = x + (size_t)arow * DIM + ac;
  const int awoff = ar * 40 + ac;
  // B-stage
  const int br = tid >> 1;
  const int bc = (tid & 1) * 16;
  const unsigned short* bp = wt_row(WtBase, n0 + br) + bc;
  const int bwoff = br * 40 + bc;

  const int wv = tid >> 6, ln = tid & 63;
  const int wr = wv >> 1, wc = wv & 1;
  const int lr = ln & 15, lg = ln >> 4;

  f32x4 acc[4][4];
#pragma unroll
  for (int i = 0; i < 4; ++i)
#pragma unroll
    for (int j = 0; j < 4; ++j) acc[i][j] = (f32x4){0.f, 0.f, 0.f, 0.f};

  // prologue: stage step 0 into buf 0
  {
    float4 f0 = *reinterpret_cast<const float4*>(ap);
    float4 f1 = *reinterpret_cast<const float4*>(ap + 4);
    float4 f2 = *reinterpret_cast<const float4*>(ap + 8);
    float4 f3 = *reinterpret_cast<const float4*>(ap + 12);
    u16x8 w0 = *reinterpret_cast<const u16x8*>(bp);
    u16x8 w1 = *reinterpret_cast<const u16x8*>(bp + 8);
    u16x8 a0, a1;
    a0[0]=f2bf_fast(f0.x); a0[1]=f2bf_fast(f0.y); a0[2]=f2bf_fast(f0.z); a0[3]=f2bf_fast(f0.w);
    a0[4]=f2bf_fast(f1.x); a0[5]=f2bf_fast(f1.y); a0[6]=f2bf_fast(f1.z); a0[7]=f2bf_fast(f1.w);
    a1[0]=f2bf_fast(f2.x); a1[1]=f2bf_fast(f2.y); a1[2]=f2bf_fast(f2.z); a1[3]=f2bf_fast(f2.w);
    a1[4]=f2bf_fast(f3.x); a1[5]=f2bf_fast(f3.y); a1[6]=f2bf_fast(f3.z); a1[7]=f2bf_fast(f3.w);
    *reinterpret_cast<u16x8*>(&As[0][awoff]) = a0;
    *reinterpret_cast<u16x8*>(&As[0][awoff + 8]) = a1;
    *reinterpret_cast<u16x8*>(&Bs[0][bwoff]) = w0;
    *reinterpret_cast<u16x8*>(&Bs[0][bwoff + 8]) = w1;
  }
  __syncthreads();

  int p = 0;
  for (int s = 0; s < 16; ++s) {
    // 1. issue global loads for step s+1
    float4 f0, f1, f2, f3; u16x8 w0, w1;
    const bool pre = (s < 15);
    if (pre) {
      int k0 = (s + 1) * 32;
      f0 = *reinterpret_cast<const float4*>(ap + k0);
      f1 = *reinterpret_cast<const float4*>(ap + k0 + 4);
      f2 = *reinterpret_cast<const float4*>(ap + k0 + 8);
      f3 = *reinterpret_cast<const float4*>(ap + k0 + 12);
      w0 = *reinterpret_cast<const u16x8*>(bp + k0);
      w1 = *reinterpret_cast<const u16x8*>(bp + k0 + 8);
    }
    // 2. fragment ds_reads from buf p
    const unsigned short* asp = As[p];
    const unsigned short* bsp = Bs[p];
    bf16x8 af[4], bf[4];
#pragma unroll
    for (int mt = 0; mt < 4; ++mt)
      af[mt] = *reinterpret_cast<const bf16x8*>(asp + (wr * 64 + mt * 16 + lr) * 40 + lg * 8);
#pragma unroll
    for (int nt = 0; nt < 4; ++nt)
      bf[nt] = *reinterpret_cast<const bf16x8*>(bsp + (wc * 64 + nt * 16 + lr) * 40 + lg * 8);
    // 3. MFMA
#pragma unroll
    for (int mt = 0; mt < 4; ++mt)
#pragma unroll
      for (int nt = 0; nt < 4; ++nt)
        acc[mt][nt] = MFMA_BF16(af[mt], bf[nt], acc[mt][nt], 0, 0, 0);
    // 4. cast + ds_write into buf p^1
    if (pre) {
      u16x8 a0, a1;
      a0[0]=f2bf_fast(f0.x); a0[1]=f2bf_fast(f0.y); a0[2]=f2bf_fast(f0.z); a0[3]=f2bf_fast(f0.w);
      a0[4]=f2bf_fast(f1.x); a0[5]=f2bf_fast(f1.y); a0[6]=f2bf_fast(f1.z); a0[7]=f2bf_fast(f1.w);
      a1[0]=f2bf_fast(f2.x); a1[1]=f2bf_fast(f2.y); a1[2]=f2bf_fast(f2.z); a1[3]=f2bf_fast(f2.w);
      a1[4]=f2bf_fast(f3.x); a1[5]=f2bf_fast(f3.y); a1[6]=f2bf_fast(f3.z); a1[7]=f2bf_fast(f3.w);
      unsigned short* dA = As[p ^ 1];
      unsigned short* dB = Bs[p ^ 1];
      *reinterpret_cast<u16x8*>(&dA[awoff]) = a0;
      *reinterpret_cast<u16x8*>(&dA[awoff + 8]) = a1;
      *reinterpret_cast<u16x8*>(&dB[bwoff]) = w0;
      *reinterpret_cast<u16x8*>(&dB[bwoff + 8]) = w1;
    }
    __syncthreads();
    p ^= 1;
  }

  // epilogue
  unsigned short* dst; int nbase;
  if (n0 < 512)       { dst = Qb; nbase = 0; }
  else if (n0 < 1024) { dst = Kb; nbase = 512; }
  else                { dst = Vb; nbase = 1024; }
  const int colg0 = n0 + wc * 64 - nbase;
#pragma unroll
  for (int mt = 0; mt < 4; ++mt) {
#pragma unroll
    for (int e = 0; e < 4; ++e) {
      unsigned rd = m0 + wr * 64 + mt * 16 + lg * 4 + e;
      if (rd < MD) {
        unsigned bb = rd / 3900u;
        unsigned tt = rd - bb * 3900u;
        size_t rowoff = ((size_t)bb * NP + tt) * DIM;
#pragma unroll
        for (int nt = 0; nt < 4; ++nt)
          dst[rowoff + colg0 + nt * 16 + lr] = f2bf(acc[mt][nt][e]);
      }
    }
  }
}

// ---------------------------------------------------------------------------
// Kernel 3: output projection, bf16 MFMA.  out = Ob @ WoT^T + bias (fp32 out).
// ---------------------------------------------------------------------------
__global__ __launch_bounds__(256) void gemm_out(
    const unsigned short* __restrict__ Ob, const unsigned short* __restrict__ WoBase,
    const float* __restrict__ bias, float* __restrict__ out)
{
  __shared__ unsigned short As[2][128 * 40];
  __shared__ unsigned short Bs[2][128 * 40];

  int bid = blockIdx.x;                       // 1952 = 8 * 244
  bid = (bid & 7) * 244 + (bid >> 3);
  const int bm = bid / 4, bn = bid % 4;
  const int m0 = bm * 128;
  const int n0 = bn * 128;
  const int tid = threadIdx.x;

  const int ar = tid >> 1;
  const int ac = (tid & 1) * 16;
  unsigned arow = m0 + ar; if (arow > MD - 1) arow = MD - 1;
  unsigned abb = arow / 3900u;
  unsigned att = arow - abb * 3900u;
  const unsigned short* ap = Ob + ((size_t)abb * NP + att) * DIM + ac;
  const int awoff = ar * 40 + ac;

  const int br = tid >> 1;
  const int bc = (tid & 1) * 16;
  const unsigned short* bp = wt_row(WoBase, n0 + br) + bc;
  const int bwoff = br * 40 + bc;

  const int wv = tid >> 6, ln = tid & 63;
  const int wr = wv >> 1, wc = wv & 1;
  const int lr = ln & 15, lg = ln >> 4;

  f32x4 acc[4][4];
#pragma unroll
  for (int i = 0; i < 4; ++i)
#pragma unroll
    for (int j = 0; j < 4; ++j) acc[i][j] = (f32x4){0.f, 0.f, 0.f, 0.f};

  {
    u16x8 a0 = *reinterpret_cast<const u16x8*>(ap);
    u16x8 a1 = *reinterpret_cast<const u16x8*>(ap + 8);
    u16x8 w0 = *reinterpret_cast<const u16x8*>(bp);
    u16x8 w1 = *reinterpret_cast<const u16x8*>(bp + 8);
    *reinterpret_cast<u16x8*>(&As[0][awoff]) = a0;
    *reinterpret_cast<u16x8*>(&As[0][awoff + 8]) = a1;
    *reinterpret_cast<u16x8*>(&Bs[0][bwoff]) = w0;
    *reinterpret_cast<u16x8*>(&Bs[0][bwoff + 8]) = w1;
  }
  __syncthreads();

  int p = 0;
  for (int s = 0; s < 16; ++s) {
    u16x8 a0, a1, w0, w1;
    const bool pre = (s < 15);
    if (pre) {
      int k0 = (s + 1) * 32;
      a0 = *reinterpret_cast<const u16x8*>(ap + k0);
      a1 = *reinterpret_cast<const u16x8*>(ap + k0 + 8);
      w0 = *reinterpret_cast<const u16x8*>(bp + k0);
      w1 = *reinterpret_cast<const u16x8*>(bp + k0 + 8);
    }
    const unsigned short* asp = As[p];
    const unsigned short* bsp = Bs[p];
    bf16x8 af[4], bf[4];
#pragma unroll
    for (int mt = 0; mt < 4; ++mt)
      af[mt] = *reinterpret_cast<const bf16x8*>(asp + (wr * 64 + mt * 16 + lr) * 40 + lg * 8);
#pragma unroll
    for (int nt = 0; nt < 4; ++nt)
      bf[nt] = *reinterpret_cast<const bf16x8*>(bsp + (wc * 64 + nt * 16 + lr) * 40 + lg * 8);
#pragma unroll
    for (int mt = 0; mt < 4; ++mt)
#pragma unroll
      for (int nt = 0; nt < 4; ++nt)
        acc[mt][nt] = MFMA_BF16(af[mt], bf[nt], acc[mt][nt], 0, 0, 0);
    if (pre) {
      unsigned short* dA = As[p ^ 1];
      unsigned short* dB = Bs[p ^ 1];
      *reinterpret_cast<u16x8*>(&dA[awoff]) = a0;
      *reinterpret_cast<u16x8*>(&dA[awoff + 8]) = a1;
      *reinterpret_cast<u16x8*>(&dB[bwoff]) = w0;
      *reinterpret_cast<u16x8*>(&dB[bwoff + 8]) = w1;
    }
    __syncthreads();
    p ^= 1;
  }

  float bv[4];
#pragma unroll
  for (int nt = 0; nt < 4; ++nt) bv[nt] = bias[n0 + wc * 64 + nt * 16 + lr];
#pragma unroll
  for (int mt = 0; mt < 4; ++mt) {
#pragma unroll
    for (int e = 0; e < 4; ++e) {
      unsigned rd = m0 + wr * 64 + mt * 16 + lg * 4 + e;
      if (rd < MD) {
#pragma unroll
        for (int nt = 0; nt < 4; ++nt)
          out[(size_t)rd * DIM + n0 + wc * 64 + nt * 16 + lr] = acc[mt][nt][e] + bv[nt];
      }
    }
  }
}

// ---------------------------------------------------------------------------
// Kernel 2: MFMA attention (unchanged from round 3 -- passing).
// ---------------------------------------------------------------------------
#define KS_U16 12800
#define VT_U16 13568
#define PQ_STR 228
#define PQ_U16 (16*PQ_STR)
#define ATTN_LDS_B ((KS_U16 + VT_U16 + 4*PQ_U16) * 2)   // 81920

__global__ __launch_bounds__(256) void attn_mfma(
    const unsigned short* __restrict__ Qb, const unsigned short* __restrict__ Kb,
    const unsigned short* __restrict__ Vb, const unsigned short* __restrict__ Tb,
    unsigned short* __restrict__ Ob)
{
  extern __shared__ unsigned short smem[];
  unsigned short* Ks = smem;
  unsigned short* Vt = smem + KS_U16;

  const int tid = threadIdx.x;
  const int bid = blockIdx.x;
  const int h  = bid & 7;
  const int bm = bid >> 3;
  const int m  = bm % NB;
  const int b  = bm / NB;
  const size_t rowbase = (size_t)b * NP + (size_t)m * CHUNK;
  const int lim = (m == NB - 1) ? NR : CHUNK;

  for (int c = tid; c < CHUNK * 8; c += 256) {
    int j = c >> 3, k0 = (c & 7) * 8;
    uint4 kv = *reinterpret_cast<const uint4*>(Kb + (rowbase + j) * DIM + h * DH + k0);
    int byte = (j * 128 + k0 * 2) ^ ((j & 7) << 4);
    *reinterpret_cast<uint4*>(reinterpret_cast<char*>(Ks) + byte) = kv;
    uint4 vv4 = *reinterpret_cast<const uint4*>(Vb + (rowbase + j) * DIM + h * DH + k0);
    const unsigned short* vs = reinterpret_cast<const unsigned short*>(&vv4);
#pragma unroll
    for (int e = 0; e < 8; ++e)
      Vt[(k0 + e) * 212 + j] = vs[e];
  }
  __syncthreads();

  const int wv = tid >> 6, ln = tid & 63;
  const int lr = ln & 15, lg = ln >> 4;
  unsigned short* pq = smem + KS_U16 + VT_U16 + wv * PQ_U16;

  const int nMt = (lim + 15) >> 4;
  for (int mt = wv; mt < nMt; mt += 4) {
    const int i0 = mt << 4;

    const unsigned short* qp = Qb + (rowbase + i0 + lr) * DIM + h * DH + lg * 8;
    bf16x8 qa0 = *reinterpret_cast<const bf16x8*>(qp);
    bf16x8 qa1 = *reinterpret_cast<const bf16x8*>(qp + 32);

#pragma unroll
    for (int ct = 0; ct < 14; ++ct) {
      const unsigned short* tp = Tb + (size_t)(i0 + ct * 16 + lr) * 64 + lg * 8;
      bf16x8 tb0 = *reinterpret_cast<const bf16x8*>(tp);
      bf16x8 tb1 = *reinterpret_cast<const bf16x8*>(tp + 32);
      f32x4 acc = {0.f, 0.f, 0.f, 0.f};
      acc = MFMA_BF16(qa0, tb0, acc, 0, 0, 0);
      acc = MFMA_BF16(qa1, tb1, acc, 0, 0, 0);
#pragma unroll
      for (int e = 0; e < 4; ++e)
        pq[(lg * 4 + e) * PQ_STR + ct * 16 + lr] = f2bf(acc[e]);
    }

    f32x4 s[13];
#pragma unroll
    for (int nt = 0; nt < 13; ++nt) {
      int row = nt * 16 + lr;
      int b0 = (row * 128 + lg * 16) ^ ((row & 7) << 4);
      int b1 = (row * 128 + 64 + lg * 16) ^ ((row & 7) << 4);
      bf16x8 k0 = *reinterpret_cast<const bf16x8*>(reinterpret_cast<char*>(Ks) + b0);
      bf16x8 k1 = *reinterpret_cast<const bf16x8*>(reinterpret_cast<char*>(Ks) + b1);
      f32x4 acc = {0.f, 0.f, 0.f, 0.f};
      acc = MFMA_BF16(qa0, k0, acc, 0, 0, 0);
      acc = MFMA_BF16(qa1, k1, acc, 0, 0, 0);
      s[nt] = acc;
    }

#pragma unroll
    for (int nt = 0; nt < 13; ++nt) {
      int j = nt * 16 + lr;
#pragma unroll
      for (int e = 0; e < 4; ++e) {
        int r = lg * 4 + e;
        float pos = bf2f(pq[r * PQ_STR + (r - j + 207)]);
        float v = (s[nt][e] + pos) * 0.125f;
        s[nt][e] = (j < lim) ? v : -INFINITY;
      }
    }

    float sum[4];
#pragma unroll
    for (int e = 0; e < 4; ++e) {
      float mv = s[0][e];
#pragma unroll
      for (int nt = 1; nt < 13; ++nt) mv = fmaxf(mv, s[nt][e]);
      mv = fmaxf(mv, __shfl_xor(mv, 1));
      mv = fmaxf(mv, __shfl_xor(mv, 2));
      mv = fmaxf(mv, __shfl_xor(mv, 4));
      mv = fmaxf(mv, __shfl_xor(mv, 8));
      float sv = 0.f;
#pragma unroll
      for (int nt = 0; nt < 13; ++nt) {
        float p = __expf(s[nt][e] - mv);
        s[nt][e] = p;
        sv += p;
      }
      sv += __shfl_xor(sv, 1);
      sv += __shfl_xor(sv, 2);
      sv += __shfl_xor(sv, 4);
      sv += __shfl_xor(sv, 8);
      sum[e] = sv;
    }

#pragma unroll
    for (int nt = 0; nt < 13; ++nt)
#pragma unroll
      for (int e = 0; e < 4; ++e)
        pq[(lg * 4 + e) * PQ_STR + nt * 16 + lr] = f2bf(s[nt][e]);

    f32x4 o[4];
#pragma unroll
    for (int nt = 0; nt < 4; ++nt) o[nt] = (f32x4){0.f, 0.f, 0.f, 0.f};
    const ushort4 zz = {0, 0, 0, 0};
#pragma unroll
    for (int ks = 0; ks < 7; ++ks) {
      union __align__(16) { struct { ushort4 lo, hi; } u; bf16x8 v; } pa;
      if (ks < 6 || lg < 2) {
        const char* pap = reinterpret_cast<const char*>(pq) + lr * (PQ_STR * 2) + ks * 64 + lg * 16;
        pa.u.lo = *reinterpret_cast<const ushort4*>(pap);
        pa.u.hi = *reinterpret_cast<const ushort4*>(pap + 8);
      } else {
        pa.u.lo = zz; pa.u.hi = zz;
      }
#pragma unroll
      for (int nt = 0; nt < 4; ++nt) {
        union __align__(16) { struct { ushort4 lo, hi; } u; bf16x8 v; } vb;
        if (ks < 6 || lg == 0) {
          const char* vbp = reinterpret_cast<const char*>(Vt) + (nt * 16 + lr) * 424 + ks * 64 + lg * 16;
          vb.u.lo = *reinterpret_cast<const ushort4*>(vbp);
          vb.u.hi = *reinterpret_cast<const ushort4*>(vbp + 8);
        } else {
          vb.u.lo = zz; vb.u.hi = zz;
        }
        o[nt] = MFMA_BF16(pa.v, vb.v, o[nt], 0, 0, 0);
      }
    }

#pragma unroll
    for (int nt = 0; nt < 4; ++nt)
#pragma unroll
      for (int e = 0; e < 4; ++e) {
        int i = i0 + lg * 4 + e;
        if (i < lim) {
          float val = o[nt][e] / sum[e];
          Ob[(rowbase + i) * DIM + h * DH + nt * 16 + lr] = f2bf(val);
        }
      }
  }
}

// ---------------------------------------------------------------------------
extern "C" void kernel_launch(void* const* d_in, const int* in_sizes, int n_in,
                              void* d_out, int out_size, void* d_ws, size_t ws_size,
                              hipStream_t stream) {
  const float* x   = (const float*)d_in[0];
  const float* wq  = (const float*)d_in[1];
  const float* wkv = (const float*)d_in[2];
  const float* wo  = (const float*)d_in[3];
  const float* wb  = (const float*)d_in[4];
  const float* tbl = (const float*)d_in[5];
  float* out = (float*)d_out;

  const size_t elems = (size_t)BS * NP * DIM;
  unsigned short* Qb = (unsigned short*)d_ws;
  unsigned short* Kb = Qb + elems;
  unsigned short* Vb = Kb + elems;
  unsigned short* Ob = Qb;                       // attn output aliases Q dense rows
  unsigned short* Tb = Kb + (size_t)SEQ * DIM;   // table window in Kb pads (b=0)
  // Wt  (1536x512 bf16) lives in Qb pad chunks 0..15
  // WoT (512x512  bf16) lives in Vb pad chunks 0..5

  hipFuncSetAttribute(reinterpret_cast<const void*>(attn_mfma),
                      hipFuncAttributeMaxDynamicSharedMemorySize, ATTN_LDS_B);

  dim3 blk(256);
  prep_table<<<dim3(26), blk, 0, stream>>>(tbl, Tb);
  wtrans<<<dim3(8, 8),  blk, 0, stream>>>(wq,  512,  0,   Qb);
  wtrans<<<dim3(16, 8), blk, 0, stream>>>(wkv, 1024, 512, Qb);
  wtrans<<<dim3(8, 8),  blk, 0, stream>>>(wo,  512,  0,   Vb);
  gemm_qkv<<<dim3(5856), blk, 0, stream>>>(x, Qb, Qb, Kb, Vb);
  attn_mfma<<<dim3(BS * NB * NHEAD), blk, ATTN_LDS_B, stream>>>(Qb, Kb, Vb, Tb, Ob);
  gemm_out<<<dim3(1952), blk, 0, stream>>>(Ob, Vb, wb, out);
}